// Round 5
// baseline (503.805 us; speedup 1.0000x reference)
//
#include <hip/hip_runtime.h>

#define DIMK 512
#define NCH  8192
#define MTOT 4096   // BATCH*SEQ = 2*2048
#define SEQL 2048
#define KS   4      // outproj K-splits

typedef __attribute__((ext_vector_type(8))) short bf16x8;
typedef __attribute__((ext_vector_type(4))) float f32x4;
typedef unsigned int uint32;

__device__ __forceinline__ unsigned short f2bf(float f) {
  unsigned int u = __float_as_uint(f);
  u += 0x7fffu + ((u >> 16) & 1u);
  return (unsigned short)(u >> 16);
}
__device__ __forceinline__ float bf2f(unsigned short v) {
  return __uint_as_float(((unsigned int)v) << 16);
}

// ---------------- fused f32 -> bf16 convert, all 6 tensors in one launch ----------------
struct CvtArgs {
  const float* src[6];
  unsigned short* dst[6];
  int cum[7];   // cumulative item counts (1 item = 8 elems)
};
__global__ __launch_bounds__(256) void cvt_all_kernel(CvtArgs a, int tot) {
  const int stride = gridDim.x * 256;
  for (int i = blockIdx.x * 256 + threadIdx.x; i < tot; i += stride) {
    int s = 0;
    while (i >= a.cum[s + 1]) ++s;
    const int j = i - a.cum[s];
    const float4* sp = reinterpret_cast<const float4*>(a.src[s]);
    float4 v0 = sp[2 * j], v1 = sp[2 * j + 1];
    union { unsigned short us[8]; uint4 v; } o;
    o.us[0] = f2bf(v0.x); o.us[1] = f2bf(v0.y); o.us[2] = f2bf(v0.z); o.us[3] = f2bf(v0.w);
    o.us[4] = f2bf(v1.x); o.us[5] = f2bf(v1.y); o.us[6] = f2bf(v1.z); o.us[7] = f2bf(v1.w);
    reinterpret_cast<uint4*>(a.dst[s])[j] = o.v;
  }
}

// swizzle: logical (row, q) lives at linear slot (row, q ^ ((row>>2)&3)); q = 16B unit
__device__ __forceinline__ int swz(int row, int q) { return q ^ ((row >> 2) & 3); }

// ---------------- fused 4-way projection GEMM + SSM epilogue ----------------
// XCD-bound n-panels: each XCD owns n%8==xcd panels -> W stays in that XCD's L2.
#define PLDS_A 4096            // 128*32 elems
#define PLDS_W 8192            // 4*64*32 elems
#define PLDS   (PLDS_A + PLDS_W)
__global__ __launch_bounds__(256) void proj_kernel(
    const unsigned short* __restrict__ xb,
    const unsigned short* __restrict__ w4,
    const float* __restrict__ b_dt, const float* __restrict__ b_B,
    const float* __restrict__ b_C, const float* __restrict__ b_V,
    const float* __restrict__ A_log,
    uint32* __restrict__ au,             // [4096][8192] u32: (vlog bf16)<<16 | (u bf16)
    unsigned short* __restrict__ c_out)  // [4096][8192] bf16: zC
{
  __shared__ __align__(16) unsigned short lds[3][PLDS];
  const int tid = threadIdx.x;
  const int lane = tid & 63;
  const int wave = tid >> 6;
  const int wr = wave >> 1, wc = wave & 1;
  // XCD-aware decode: assumes linear-id round-robin over 8 XCDs (perf-only)
  const int id = blockIdx.x;
  const int xcd = id & 7, j = id >> 3;
  const int n0 = ((j >> 5) * 8 + xcd) * 64;   // n-panel bound to one XCD
  const int m0 = (j & 31) * 128;

  auto stage = [&](int buf, int kt) {
    const int k0 = kt * 32;
    #pragma unroll
    for (int i = 0; i < 2; ++i) {            // A tile: 128x32
      int c = i * 256 + tid;
      int row = c >> 2, q = c & 3;
      const unsigned short* g = xb + (size_t)(m0 + row) * DIMK + k0 + swz(row, q) * 8;
      __builtin_amdgcn_global_load_lds(
          (const __attribute__((address_space(1))) void*)g,
          (__attribute__((address_space(3))) void*)&lds[buf][c * 8], 16, 0, 0);
    }
    #pragma unroll
    for (int p = 0; p < 4; ++p) {            // W tiles: 4 x 64x32
      int row = tid >> 2, q = tid & 3;
      const unsigned short* g = w4 + ((size_t)p * NCH + n0 + row) * DIMK + k0 + swz(row, q) * 8;
      __builtin_amdgcn_global_load_lds(
          (const __attribute__((address_space(1))) void*)g,
          (__attribute__((address_space(3))) void*)&lds[buf][PLDS_A + p * 2048 + tid * 8], 16, 0, 0);
    }
  };

  f32x4 acc[4][4][2];
  #pragma unroll
  for (int p = 0; p < 4; ++p)
    #pragma unroll
    for (int fm = 0; fm < 4; ++fm)
      #pragma unroll
      for (int fn = 0; fn < 2; ++fn)
        acc[p][fm][fn] = (f32x4){0.f, 0.f, 0.f, 0.f};

  stage(0, 0);
  stage(1, 1);
  constexpr int NKT = DIMK / 32;   // 16
  #pragma unroll 1
  for (int kt = 0; kt < NKT; ++kt) {
    const int buf = kt % 3;
    if (kt < NKT - 1) asm volatile("s_waitcnt vmcnt(6)" ::: "memory");
    else              asm volatile("s_waitcnt vmcnt(0)" ::: "memory");
    __builtin_amdgcn_s_barrier();
    if (kt + 2 < NKT) stage((kt + 2) % 3, kt + 2);   // issue-early, 2 ahead

    const int arow = wr * 64 + (lane & 15);
    const int qq = lane >> 4;
    bf16x8 af[4];
    #pragma unroll
    for (int fm = 0; fm < 4; ++fm) {
      const int r = arow + fm * 16;
      af[fm] = *reinterpret_cast<const bf16x8*>(&lds[buf][r * 32 + swz(r, qq) * 8]);
    }
    #pragma unroll
    for (int p = 0; p < 4; ++p) {
      bf16x8 bfr[2];
      #pragma unroll
      for (int fn = 0; fn < 2; ++fn) {
        const int r = wc * 32 + fn * 16 + (lane & 15);
        bfr[fn] = *reinterpret_cast<const bf16x8*>(
            &lds[buf][PLDS_A + p * 2048 + r * 32 + swz(r, qq) * 8]);
      }
      __builtin_amdgcn_s_setprio(1);
      #pragma unroll
      for (int fm = 0; fm < 4; ++fm)
        #pragma unroll
        for (int fn = 0; fn < 2; ++fn)
          acc[p][fm][fn] = __builtin_amdgcn_mfma_f32_16x16x32_bf16(
              af[fm], bfr[fn], acc[p][fm][fn], 0, 0, 0);
      __builtin_amdgcn_s_setprio(0);
    }
    asm volatile("s_waitcnt lgkmcnt(0)" ::: "memory");
  }

  // epilogue: dt = softplus(zdt); au = pack(dt*A_log, dt*zB*zV); c = zC
  #pragma unroll
  for (int fn = 0; fn < 2; ++fn) {
    const int n = n0 + wc * 32 + fn * 16 + (lane & 15);
    const float vbdt = b_dt[n], vbB = b_B[n], vbC = b_C[n], vbV = b_V[n];
    const float al = A_log[n];
    #pragma unroll
    for (int fm = 0; fm < 4; ++fm) {
      const int mbase = m0 + wr * 64 + fm * 16 + (lane >> 4) * 4;
      #pragma unroll
      for (int r = 0; r < 4; ++r) {
        const size_t off = (size_t)(mbase + r) * NCH + n;
        const float zdt = acc[0][fm][fn][r] + vbdt;
        const float zB  = acc[1][fm][fn][r] + vbB;
        const float zC  = acc[2][fm][fn][r] + vbC;
        const float zV  = acc[3][fm][fn][r] + vbV;
        const float dt = (zdt > 15.f) ? zdt : __logf(1.f + __expf(zdt));
        au[off] = ((uint32)f2bf(dt * al) << 16) | (uint32)f2bf(dt * zB * zV);
        c_out[off] = f2bf(zC);
      }
    }
  }
}

// ---------------- chunked parallel scan ----------------
#define SCH 16
#define CSTEPS 128
__global__ __launch_bounds__(1024) void scan_kernel(
    const uint32* __restrict__ au,
    unsigned short* cy)
{
  __shared__ float Ap[SCH][64], He[SCH][64], H0[SCH][64];
  const int lane = threadIdx.x & 63;
  const int w = threadIdx.x >> 6;
  const int c = blockIdx.x * 64 + lane;
  const size_t base = (size_t)blockIdx.y * SEQL * NCH + (size_t)(w * CSTEPS) * NCH + c;

  {
    const uint32* ap = au + base;
    float h = 0.f, vsum = 0.f;
    #pragma unroll 1
    for (int s = 0; s < CSTEPS; s += 8) {
      uint32 wv[8];
      #pragma unroll
      for (int i = 0; i < 8; ++i) wv[i] = ap[(size_t)(s + i) * NCH];
      #pragma unroll
      for (int i = 0; i < 8; ++i) {
        const float av = bf2f((unsigned short)(wv[i] >> 16));
        const float uv = bf2f((unsigned short)(wv[i] & 0xffff));
        vsum += av;
        h = fmaf(__expf(av), h, uv);
      }
    }
    Ap[w][lane] = __expf(vsum);
    He[w][lane] = h;
  }
  __syncthreads();
  if (w == 0) {
    float run = 0.f;
    #pragma unroll
    for (int jj = 0; jj < SCH; ++jj) {
      H0[jj][lane] = run;
      run = fmaf(Ap[jj][lane], run, He[jj][lane]);
    }
  }
  __syncthreads();
  {
    const uint32* ap = au + base;
    unsigned short* cp = cy + base;
    float h = H0[w][lane];
    #pragma unroll 1
    for (int s = 0; s < CSTEPS; s += 8) {
      uint32 wv[8];
      float cv[8];
      #pragma unroll
      for (int i = 0; i < 8; ++i) {
        wv[i] = ap[(size_t)(s + i) * NCH];
        cv[i] = bf2f(cp[(size_t)(s + i) * NCH]);
      }
      #pragma unroll
      for (int i = 0; i < 8; ++i) {
        const float av = bf2f((unsigned short)(wv[i] >> 16));
        const float uv = bf2f((unsigned short)(wv[i] & 0xffff));
        h = fmaf(__expf(av), h, uv);
        cv[i] *= h;
      }
      #pragma unroll
      for (int i = 0; i < 8; ++i) cp[(size_t)(s + i) * NCH] = f2bf(cv[i]);
    }
  }
}

// ---------------- output projection, split-K ----------------
#define OLDS_A 4096   // 128*32
#define OLDS_B 2048   // 64*32
#define OLDS   (OLDS_A + OLDS_B)
__global__ __launch_bounds__(256) void outproj_kernel(
    const unsigned short* __restrict__ yb,    // [4096][8192] bf16
    const unsigned short* __restrict__ wout,  // [512][8192] bf16
    float* __restrict__ partial)              // [KS][4096][512] f32
{
  __shared__ __align__(16) unsigned short lds[3][OLDS];
  const int tid = threadIdx.x;
  const int lane = tid & 63;
  const int wave = tid >> 6;
  const int wr = wave >> 1, wc = wave & 1;
  const int m0 = blockIdx.x * 128;
  const int d0 = blockIdx.y * 64;
  const int kbase = blockIdx.z * (NCH / KS);   // 2048 per split

  auto stage = [&](int buf, int kt) {
    const int k0 = kbase + kt * 32;
    #pragma unroll
    for (int i = 0; i < 2; ++i) {
      int c = i * 256 + tid;
      int row = c >> 2, q = c & 3;
      const unsigned short* g = yb + (size_t)(m0 + row) * NCH + k0 + swz(row, q) * 8;
      __builtin_amdgcn_global_load_lds(
          (const __attribute__((address_space(1))) void*)g,
          (__attribute__((address_space(3))) void*)&lds[buf][c * 8], 16, 0, 0);
    }
    {
      int row = tid >> 2, q = tid & 3;
      const unsigned short* g = wout + (size_t)(d0 + row) * NCH + k0 + swz(row, q) * 8;
      __builtin_amdgcn_global_load_lds(
          (const __attribute__((address_space(1))) void*)g,
          (__attribute__((address_space(3))) void*)&lds[buf][OLDS_A + tid * 8], 16, 0, 0);
    }
  };

  f32x4 acc[4][2];
  #pragma unroll
  for (int fm = 0; fm < 4; ++fm)
    #pragma unroll
    for (int fn = 0; fn < 2; ++fn) acc[fm][fn] = (f32x4){0.f, 0.f, 0.f, 0.f};

  stage(0, 0);
  stage(1, 1);
  constexpr int NKT = (NCH / KS) / 32;   // 64
  #pragma unroll 1
  for (int kt = 0; kt < NKT; ++kt) {
    const int buf = kt % 3;
    if (kt < NKT - 1) asm volatile("s_waitcnt vmcnt(3)" ::: "memory");
    else              asm volatile("s_waitcnt vmcnt(0)" ::: "memory");
    __builtin_amdgcn_s_barrier();
    if (kt + 2 < NKT) stage((kt + 2) % 3, kt + 2);

    const int qq = lane >> 4;
    bf16x8 af[4], bfr[2];
    #pragma unroll
    for (int fm = 0; fm < 4; ++fm) {
      const int r = wr * 64 + fm * 16 + (lane & 15);
      af[fm] = *reinterpret_cast<const bf16x8*>(&lds[buf][r * 32 + swz(r, qq) * 8]);
    }
    #pragma unroll
    for (int fn = 0; fn < 2; ++fn) {
      const int r = wc * 32 + fn * 16 + (lane & 15);
      bfr[fn] = *reinterpret_cast<const bf16x8*>(
          &lds[buf][OLDS_A + r * 32 + swz(r, qq) * 8]);
    }
    __builtin_amdgcn_s_setprio(1);
    #pragma unroll
    for (int fm = 0; fm < 4; ++fm)
      #pragma unroll
      for (int fn = 0; fn < 2; ++fn)
        acc[fm][fn] = __builtin_amdgcn_mfma_f32_16x16x32_bf16(
            af[fm], bfr[fn], acc[fm][fn], 0, 0, 0);
    __builtin_amdgcn_s_setprio(0);
    asm volatile("s_waitcnt lgkmcnt(0)" ::: "memory");
  }

  float* pout = partial + (size_t)blockIdx.z * MTOT * DIMK;
  #pragma unroll
  for (int fn = 0; fn < 2; ++fn) {
    const int d = d0 + wc * 32 + fn * 16 + (lane & 15);
    #pragma unroll
    for (int fm = 0; fm < 4; ++fm) {
      const int mbase = m0 + wr * 64 + fm * 16 + (lane >> 4) * 4;
      #pragma unroll
      for (int r = 0; r < 4; ++r)
        pout[(size_t)(mbase + r) * DIMK + d] = acc[fm][fn][r];
    }
  }
}

// ---------------- split-K reduce + bias ----------------
__global__ __launch_bounds__(256) void reduce_kernel(
    const float* __restrict__ p, const float* __restrict__ bias,
    float* __restrict__ out)
{
  const int i = blockIdx.x * 256 + threadIdx.x;   // float4 index, 524288 total
  const float4* p4 = reinterpret_cast<const float4*>(p);
  float4 s = p4[i];
  #pragma unroll
  for (int k = 1; k < KS; ++k) {
    float4 t = p4[(size_t)k * (MTOT * DIMK / 4) + i];
    s.x += t.x; s.y += t.y; s.z += t.z; s.w += t.w;
  }
  const float4 b = reinterpret_cast<const float4*>(bias)[i & 127];
  s.x += b.x; s.y += b.y; s.z += b.z; s.w += b.w;
  reinterpret_cast<float4*>(out)[i] = s;
}

extern "C" void kernel_launch(void* const* d_in, const int* in_sizes, int n_in,
                              void* d_out, int out_size, void* d_ws, size_t ws_size,
                              hipStream_t stream) {
  const float* x    = (const float*)d_in[0];
  const float* Wdt  = (const float*)d_in[1];
  const float* bdt  = (const float*)d_in[2];
  const float* WB   = (const float*)d_in[3];
  const float* bB   = (const float*)d_in[4];
  const float* WC   = (const float*)d_in[5];
  const float* bC   = (const float*)d_in[6];
  const float* WV   = (const float*)d_in[7];
  const float* bV   = (const float*)d_in[8];
  const float* Alog = (const float*)d_in[9];
  const float* Wout = (const float*)d_in[10];
  const float* bout = (const float*)d_in[11];
  float* out = (float*)d_out;

  char* ws = (char*)d_ws;
  unsigned short* woutb = (unsigned short*)(ws);               // 8 MiB
  unsigned short* xb    = (unsigned short*)(ws + 8388608);     // 4 MiB
  unsigned short* w4    = (unsigned short*)(ws + 12582912);    // 32 MiB
  char* dyn = ws + 46137344;
  uint32*         au  = (uint32*)(dyn);                        // 128 MiB
  unsigned short* cy  = (unsigned short*)(dyn + (size_t)MTOT * NCH * 4);  // 64 MiB
  float* partial = (float*)au;   // alias: au dead after scan; KS*4096*512*4 = 32 MiB

  CvtArgs ca;
  ca.src[0] = x;    ca.dst[0] = xb;
  ca.src[1] = Wdt;  ca.dst[1] = w4 + 0 * 4194304;
  ca.src[2] = WB;   ca.dst[2] = w4 + 1 * 4194304;
  ca.src[3] = WC;   ca.dst[3] = w4 + 2 * 4194304;
  ca.src[4] = WV;   ca.dst[4] = w4 + 3 * 4194304;
  ca.src[5] = Wout; ca.dst[5] = woutb;
  ca.cum[0] = 0;        ca.cum[1] = 262144;  ca.cum[2] = 786432;
  ca.cum[3] = 1310720;  ca.cum[4] = 1835008; ca.cum[5] = 2359296;
  ca.cum[6] = 2883584;
  cvt_all_kernel<<<2048, 256, 0, stream>>>(ca, 2883584);

  proj_kernel<<<4096, 256, 0, stream>>>(
      xb, w4, bdt, bB, bC, bV, Alog, au, cy);
  scan_kernel<<<dim3(NCH / 64, 2), 1024, 0, stream>>>(au, cy);
  outproj_kernel<<<dim3(MTOT / 128, DIMK / 64, KS), 256, 0, stream>>>(
      cy, woutb, partial);
  reduce_kernel<<<MTOT * DIMK / 4 / 256, 256, 0, stream>>>(partial, bout, out);
}

// Round 6
// 488.239 us; speedup vs baseline: 1.0319x; 1.0319x over previous
//
#include <hip/hip_runtime.h>

#define DIMK 512
#define NCH  8192
#define MTOT 4096   // BATCH*SEQ = 2*2048
#define SEQL 2048
#define KS   4      // outproj K-splits

typedef __attribute__((ext_vector_type(8))) short bf16x8;
typedef __attribute__((ext_vector_type(4))) float f32x4;
typedef unsigned int uint32;

__device__ __forceinline__ unsigned short f2bf(float f) {
  unsigned int u = __float_as_uint(f);
  u += 0x7fffu + ((u >> 16) & 1u);
  return (unsigned short)(u >> 16);
}
__device__ __forceinline__ float bf2f(unsigned short v) {
  return __uint_as_float(((unsigned int)v) << 16);
}

// ---------------- fused f32 -> bf16 convert, all 6 tensors in one launch ----------------
struct CvtArgs {
  const float* src[6];
  unsigned short* dst[6];
  int cum[7];   // cumulative item counts (1 item = 8 elems)
};
__global__ __launch_bounds__(256) void cvt_all_kernel(CvtArgs a, int tot) {
  const int stride = gridDim.x * 256;
  for (int i = blockIdx.x * 256 + threadIdx.x; i < tot; i += stride) {
    int s = 0;
    while (i >= a.cum[s + 1]) ++s;
    const int j = i - a.cum[s];
    const float4* sp = reinterpret_cast<const float4*>(a.src[s]);
    float4 v0 = sp[2 * j], v1 = sp[2 * j + 1];
    union { unsigned short us[8]; uint4 v; } o;
    o.us[0] = f2bf(v0.x); o.us[1] = f2bf(v0.y); o.us[2] = f2bf(v0.z); o.us[3] = f2bf(v0.w);
    o.us[4] = f2bf(v1.x); o.us[5] = f2bf(v1.y); o.us[6] = f2bf(v1.z); o.us[7] = f2bf(v1.w);
    reinterpret_cast<uint4*>(a.dst[s])[j] = o.v;
  }
}

// swizzle: logical (row, q) lives at linear slot (row, q ^ ((row>>2)&3)); q = 16B unit
__device__ __forceinline__ int swz(int row, int q) { return q ^ ((row >> 2) & 3); }

// ---------------- fused 4-way projection GEMM + SSM epilogue ----------------
// 2-buffer (48KB -> 3 blocks/CU, 12 waves/CU) counted-vmcnt pipeline.
#define PLDS_A 4096            // 128*32 elems
#define PLDS_W 8192            // 4*64*32 elems
#define PLDS   (PLDS_A + PLDS_W)
__global__ __launch_bounds__(256) void proj_kernel(
    const unsigned short* __restrict__ xb,
    const unsigned short* __restrict__ w4,
    const float* __restrict__ b_dt, const float* __restrict__ b_B,
    const float* __restrict__ b_C, const float* __restrict__ b_V,
    const float* __restrict__ A_log,
    uint32* __restrict__ au,             // [4096][8192] u32: (vlog bf16)<<16 | (u bf16)
    unsigned short* __restrict__ c_out)  // [4096][8192] bf16: zC
{
  __shared__ __align__(16) unsigned short lds[2][PLDS];
  const int tid = threadIdx.x;
  const int lane = tid & 63;
  const int wave = tid >> 6;
  const int wr = wave >> 1, wc = wave & 1;
  const int n0 = blockIdx.x * 64;
  const int m0 = blockIdx.y * 128;

  auto stage = [&](int buf, int kt) {
    const int k0 = kt * 32;
    #pragma unroll
    for (int i = 0; i < 2; ++i) {            // A tile: 128x32
      int c = i * 256 + tid;
      int row = c >> 2, q = c & 3;
      const unsigned short* g = xb + (size_t)(m0 + row) * DIMK + k0 + swz(row, q) * 8;
      __builtin_amdgcn_global_load_lds(
          (const __attribute__((address_space(1))) void*)g,
          (__attribute__((address_space(3))) void*)&lds[buf][c * 8], 16, 0, 0);
    }
    #pragma unroll
    for (int p = 0; p < 4; ++p) {            // W tiles: 4 x 64x32
      int row = tid >> 2, q = tid & 3;
      const unsigned short* g = w4 + ((size_t)p * NCH + n0 + row) * DIMK + k0 + swz(row, q) * 8;
      __builtin_amdgcn_global_load_lds(
          (const __attribute__((address_space(1))) void*)g,
          (__attribute__((address_space(3))) void*)&lds[buf][PLDS_A + p * 2048 + tid * 8], 16, 0, 0);
    }
  };

  f32x4 acc[4][4][2];
  #pragma unroll
  for (int p = 0; p < 4; ++p)
    #pragma unroll
    for (int fm = 0; fm < 4; ++fm)
      #pragma unroll
      for (int fn = 0; fn < 2; ++fn)
        acc[p][fm][fn] = (f32x4){0.f, 0.f, 0.f, 0.f};

  stage(0, 0);
  constexpr int NKT = DIMK / 32;   // 16
  #pragma unroll 1
  for (int kt = 0; kt < NKT; ++kt) {
    const int buf = kt & 1;
    if (kt + 1 < NKT) {
      stage(buf ^ 1, kt + 1);   // issue next tile first (buf^1 free since prev iter's end barrier)
      asm volatile("s_waitcnt vmcnt(6)" ::: "memory");   // wait current tile; next stays in flight
    } else {
      asm volatile("s_waitcnt vmcnt(0)" ::: "memory");
    }
    __builtin_amdgcn_s_barrier();

    const int arow = wr * 64 + (lane & 15);
    const int qq = lane >> 4;
    bf16x8 af[4];
    #pragma unroll
    for (int fm = 0; fm < 4; ++fm) {
      const int r = arow + fm * 16;
      af[fm] = *reinterpret_cast<const bf16x8*>(&lds[buf][r * 32 + swz(r, qq) * 8]);
    }
    #pragma unroll
    for (int p = 0; p < 4; ++p) {
      bf16x8 bfr[2];
      #pragma unroll
      for (int fn = 0; fn < 2; ++fn) {
        const int r = wc * 32 + fn * 16 + (lane & 15);
        bfr[fn] = *reinterpret_cast<const bf16x8*>(
            &lds[buf][PLDS_A + p * 2048 + r * 32 + swz(r, qq) * 8]);
      }
      __builtin_amdgcn_s_setprio(1);
      #pragma unroll
      for (int fm = 0; fm < 4; ++fm)
        #pragma unroll
        for (int fn = 0; fn < 2; ++fn)
          acc[p][fm][fn] = __builtin_amdgcn_mfma_f32_16x16x32_bf16(
              af[fm], bfr[fn], acc[p][fm][fn], 0, 0, 0);
      __builtin_amdgcn_s_setprio(0);
    }
    // all my reads of buf done before next iter's stage overwrites it
    asm volatile("s_waitcnt lgkmcnt(0)" ::: "memory");
    __builtin_amdgcn_s_barrier();
  }

  // epilogue: dt = softplus(zdt); au = pack(dt*A_log, dt*zB*zV); c = zC
  #pragma unroll
  for (int fn = 0; fn < 2; ++fn) {
    const int n = n0 + wc * 32 + fn * 16 + (lane & 15);
    const float vbdt = b_dt[n], vbB = b_B[n], vbC = b_C[n], vbV = b_V[n];
    const float al = A_log[n];
    #pragma unroll
    for (int fm = 0; fm < 4; ++fm) {
      const int mbase = m0 + wr * 64 + fm * 16 + (lane >> 4) * 4;
      #pragma unroll
      for (int r = 0; r < 4; ++r) {
        const size_t off = (size_t)(mbase + r) * NCH + n;
        const float zdt = acc[0][fm][fn][r] + vbdt;
        const float zB  = acc[1][fm][fn][r] + vbB;
        const float zC  = acc[2][fm][fn][r] + vbC;
        const float zV  = acc[3][fm][fn][r] + vbV;
        const float dt = (zdt > 15.f) ? zdt : __logf(1.f + __expf(zdt));
        au[off] = ((uint32)f2bf(dt * al) << 16) | (uint32)f2bf(dt * zB * zV);
        c_out[off] = f2bf(zC);
      }
    }
  }
}

// ---------------- chunked parallel scan ----------------
#define SCH 16
#define CSTEPS 128
__global__ __launch_bounds__(1024) void scan_kernel(
    const uint32* __restrict__ au,
    unsigned short* cy)
{
  __shared__ float Ap[SCH][64], He[SCH][64], H0[SCH][64];
  const int lane = threadIdx.x & 63;
  const int w = threadIdx.x >> 6;
  const int c = blockIdx.x * 64 + lane;
  const size_t base = (size_t)blockIdx.y * SEQL * NCH + (size_t)(w * CSTEPS) * NCH + c;

  {
    const uint32* ap = au + base;
    float h = 0.f, vsum = 0.f;
    #pragma unroll 1
    for (int s = 0; s < CSTEPS; s += 8) {
      uint32 wv[8];
      #pragma unroll
      for (int i = 0; i < 8; ++i) wv[i] = ap[(size_t)(s + i) * NCH];
      #pragma unroll
      for (int i = 0; i < 8; ++i) {
        const float av = bf2f((unsigned short)(wv[i] >> 16));
        const float uv = bf2f((unsigned short)(wv[i] & 0xffff));
        vsum += av;
        h = fmaf(__expf(av), h, uv);
      }
    }
    Ap[w][lane] = __expf(vsum);
    He[w][lane] = h;
  }
  __syncthreads();
  if (w == 0) {
    float run = 0.f;
    #pragma unroll
    for (int jj = 0; jj < SCH; ++jj) {
      H0[jj][lane] = run;
      run = fmaf(Ap[jj][lane], run, He[jj][lane]);
    }
  }
  __syncthreads();
  {
    const uint32* ap = au + base;
    unsigned short* cp = cy + base;
    float h = H0[w][lane];
    #pragma unroll 1
    for (int s = 0; s < CSTEPS; s += 8) {
      uint32 wv[8];
      float cv[8];
      #pragma unroll
      for (int i = 0; i < 8; ++i) {
        wv[i] = ap[(size_t)(s + i) * NCH];
        cv[i] = bf2f(cp[(size_t)(s + i) * NCH]);
      }
      #pragma unroll
      for (int i = 0; i < 8; ++i) {
        const float av = bf2f((unsigned short)(wv[i] >> 16));
        const float uv = bf2f((unsigned short)(wv[i] & 0xffff));
        h = fmaf(__expf(av), h, uv);
        cv[i] *= h;
      }
      #pragma unroll
      for (int i = 0; i < 8; ++i) cp[(size_t)(s + i) * NCH] = f2bf(cv[i]);
    }
  }
}

// ---------------- output projection, split-K, 2-buffer (24KB -> 6 blocks/CU) ----------------
#define OLDS_A 4096   // 128*32
#define OLDS_B 2048   // 64*32
#define OLDS   (OLDS_A + OLDS_B)
__global__ __launch_bounds__(256) void outproj_kernel(
    const unsigned short* __restrict__ yb,    // [4096][8192] bf16
    const unsigned short* __restrict__ wout,  // [512][8192] bf16
    float* __restrict__ partial)              // [KS][4096][512] f32
{
  __shared__ __align__(16) unsigned short lds[2][OLDS];
  const int tid = threadIdx.x;
  const int lane = tid & 63;
  const int wave = tid >> 6;
  const int wr = wave >> 1, wc = wave & 1;
  const int m0 = blockIdx.x * 128;
  const int d0 = blockIdx.y * 64;
  const int kbase = blockIdx.z * (NCH / KS);   // 2048 per split

  auto stage = [&](int buf, int kt) {
    const int k0 = kbase + kt * 32;
    #pragma unroll
    for (int i = 0; i < 2; ++i) {
      int c = i * 256 + tid;
      int row = c >> 2, q = c & 3;
      const unsigned short* g = yb + (size_t)(m0 + row) * NCH + k0 + swz(row, q) * 8;
      __builtin_amdgcn_global_load_lds(
          (const __attribute__((address_space(1))) void*)g,
          (__attribute__((address_space(3))) void*)&lds[buf][c * 8], 16, 0, 0);
    }
    {
      int row = tid >> 2, q = tid & 3;
      const unsigned short* g = wout + (size_t)(d0 + row) * NCH + k0 + swz(row, q) * 8;
      __builtin_amdgcn_global_load_lds(
          (const __attribute__((address_space(1))) void*)g,
          (__attribute__((address_space(3))) void*)&lds[buf][OLDS_A + tid * 8], 16, 0, 0);
    }
  };

  f32x4 acc[4][2];
  #pragma unroll
  for (int fm = 0; fm < 4; ++fm)
    #pragma unroll
    for (int fn = 0; fn < 2; ++fn) acc[fm][fn] = (f32x4){0.f, 0.f, 0.f, 0.f};

  stage(0, 0);
  constexpr int NKT = (NCH / KS) / 32;   // 64
  #pragma unroll 1
  for (int kt = 0; kt < NKT; ++kt) {
    const int buf = kt & 1;
    if (kt + 1 < NKT) {
      stage(buf ^ 1, kt + 1);
      asm volatile("s_waitcnt vmcnt(3)" ::: "memory");
    } else {
      asm volatile("s_waitcnt vmcnt(0)" ::: "memory");
    }
    __builtin_amdgcn_s_barrier();

    const int qq = lane >> 4;
    bf16x8 af[4], bfr[2];
    #pragma unroll
    for (int fm = 0; fm < 4; ++fm) {
      const int r = wr * 64 + fm * 16 + (lane & 15);
      af[fm] = *reinterpret_cast<const bf16x8*>(&lds[buf][r * 32 + swz(r, qq) * 8]);
    }
    #pragma unroll
    for (int fn = 0; fn < 2; ++fn) {
      const int r = wc * 32 + fn * 16 + (lane & 15);
      bfr[fn] = *reinterpret_cast<const bf16x8*>(
          &lds[buf][OLDS_A + r * 32 + swz(r, qq) * 8]);
    }
    __builtin_amdgcn_s_setprio(1);
    #pragma unroll
    for (int fm = 0; fm < 4; ++fm)
      #pragma unroll
      for (int fn = 0; fn < 2; ++fn)
        acc[fm][fn] = __builtin_amdgcn_mfma_f32_16x16x32_bf16(
            af[fm], bfr[fn], acc[fm][fn], 0, 0, 0);
    __builtin_amdgcn_s_setprio(0);
    asm volatile("s_waitcnt lgkmcnt(0)" ::: "memory");
    __builtin_amdgcn_s_barrier();
  }

  float* pout = partial + (size_t)blockIdx.z * MTOT * DIMK;
  #pragma unroll
  for (int fn = 0; fn < 2; ++fn) {
    const int d = d0 + wc * 32 + fn * 16 + (lane & 15);
    #pragma unroll
    for (int fm = 0; fm < 4; ++fm) {
      const int mbase = m0 + wr * 64 + fm * 16 + (lane >> 4) * 4;
      #pragma unroll
      for (int r = 0; r < 4; ++r)
        pout[(size_t)(mbase + r) * DIMK + d] = acc[fm][fn][r];
    }
  }
}

// ---------------- split-K reduce + bias ----------------
__global__ __launch_bounds__(256) void reduce_kernel(
    const float* __restrict__ p, const float* __restrict__ bias,
    float* __restrict__ out)
{
  const int i = blockIdx.x * 256 + threadIdx.x;   // float4 index, 524288 total
  const float4* p4 = reinterpret_cast<const float4*>(p);
  float4 s = p4[i];
  #pragma unroll
  for (int k = 1; k < KS; ++k) {
    float4 t = p4[(size_t)k * (MTOT * DIMK / 4) + i];
    s.x += t.x; s.y += t.y; s.z += t.z; s.w += t.w;
  }
  const float4 b = reinterpret_cast<const float4*>(bias)[i & 127];
  s.x += b.x; s.y += b.y; s.z += b.z; s.w += b.w;
  reinterpret_cast<float4*>(out)[i] = s;
}

extern "C" void kernel_launch(void* const* d_in, const int* in_sizes, int n_in,
                              void* d_out, int out_size, void* d_ws, size_t ws_size,
                              hipStream_t stream) {
  const float* x    = (const float*)d_in[0];
  const float* Wdt  = (const float*)d_in[1];
  const float* bdt  = (const float*)d_in[2];
  const float* WB   = (const float*)d_in[3];
  const float* bB   = (const float*)d_in[4];
  const float* WC   = (const float*)d_in[5];
  const float* bC   = (const float*)d_in[6];
  const float* WV   = (const float*)d_in[7];
  const float* bV   = (const float*)d_in[8];
  const float* Alog = (const float*)d_in[9];
  const float* Wout = (const float*)d_in[10];
  const float* bout = (const float*)d_in[11];
  float* out = (float*)d_out;

  char* ws = (char*)d_ws;
  unsigned short* woutb = (unsigned short*)(ws);               // 8 MiB
  unsigned short* xb    = (unsigned short*)(ws + 8388608);     // 4 MiB
  unsigned short* w4    = (unsigned short*)(ws + 12582912);    // 32 MiB
  char* dyn = ws + 46137344;
  uint32*         au  = (uint32*)(dyn);                        // 128 MiB
  unsigned short* cy  = (unsigned short*)(dyn + (size_t)MTOT * NCH * 4);  // 64 MiB
  float* partial = (float*)au;   // alias: au dead after scan; KS*4096*512*4 = 32 MiB

  CvtArgs ca;
  ca.src[0] = x;    ca.dst[0] = xb;
  ca.src[1] = Wdt;  ca.dst[1] = w4 + 0 * 4194304;
  ca.src[2] = WB;   ca.dst[2] = w4 + 1 * 4194304;
  ca.src[3] = WC;   ca.dst[3] = w4 + 2 * 4194304;
  ca.src[4] = WV;   ca.dst[4] = w4 + 3 * 4194304;
  ca.src[5] = Wout; ca.dst[5] = woutb;
  ca.cum[0] = 0;        ca.cum[1] = 262144;  ca.cum[2] = 786432;
  ca.cum[3] = 1310720;  ca.cum[4] = 1835008; ca.cum[5] = 2359296;
  ca.cum[6] = 2883584;
  cvt_all_kernel<<<2048, 256, 0, stream>>>(ca, 2883584);

  proj_kernel<<<dim3(NCH / 64, MTOT / 128), 256, 0, stream>>>(
      xb, w4, bdt, bB, bC, bV, Alog, au, cy);
  scan_kernel<<<dim3(NCH / 64, 2), 1024, 0, stream>>>(au, cy);
  outproj_kernel<<<dim3(MTOT / 128, DIMK / 64, KS), 256, 0, stream>>>(
      cy, woutb, partial);
  reduce_kernel<<<MTOT * DIMK / 4 / 256, 256, 0, stream>>>(partial, bout, out);
}

// Round 7
// 414.772 us; speedup vs baseline: 1.2147x; 1.1771x over previous
//
#include <hip/hip_runtime.h>

#define DIMK 512
#define NCH  8192
#define NCAT 32768  // 4*NCH interleaved
#define MTOT 4096   // BATCH*SEQ = 2*2048
#define SEQL 2048
#define KS   4      // outproj K-splits

typedef __attribute__((ext_vector_type(8))) short bf16x8;
typedef __attribute__((ext_vector_type(4))) float f32x4;
typedef unsigned int uint32;

__device__ __forceinline__ unsigned short f2bf(float f) {
  unsigned int u = __float_as_uint(f);
  u += 0x7fffu + ((u >> 16) & 1u);
  return (unsigned short)(u >> 16);
}
__device__ __forceinline__ float bf2f(unsigned short v) {
  return __uint_as_float(((unsigned int)v) << 16);
}

// ---------------- fused f32 -> bf16 convert + W-interleave ----------------
// W tensors (s=1..4, p=s-1) are written interleaved: row ch -> n_cat =
// (ch>>4)*64 + p*16 + (ch&15), so a 256-wide n-tile = 16 ch x 4 proj.
struct CvtArgs {
  const float* src[6];
  unsigned short* dst[6];
  int cum[7];   // cumulative item counts (1 item = 8 elems)
};
__global__ __launch_bounds__(256) void cvt_all_kernel(CvtArgs a, int tot) {
  const int stride = gridDim.x * 256;
  for (int i = blockIdx.x * 256 + threadIdx.x; i < tot; i += stride) {
    int s = 0;
    while (i >= a.cum[s + 1]) ++s;
    const int j = i - a.cum[s];
    const float4* sp = reinterpret_cast<const float4*>(a.src[s]);
    float4 v0 = sp[2 * j], v1 = sp[2 * j + 1];
    union { unsigned short us[8]; uint4 v; } o;
    o.us[0] = f2bf(v0.x); o.us[1] = f2bf(v0.y); o.us[2] = f2bf(v0.z); o.us[3] = f2bf(v0.w);
    o.us[4] = f2bf(v1.x); o.us[5] = f2bf(v1.y); o.us[6] = f2bf(v1.z); o.us[7] = f2bf(v1.w);
    int dj = j;
    if (s >= 1 && s <= 4) {           // interleave W rows
      const int row = j >> 6, k8 = j & 63, p = s - 1;
      const int ncat = (row >> 4) * 64 + (p << 4) + (row & 15);
      dj = ncat * 64 + k8;
    }
    reinterpret_cast<uint4*>(a.dst[s])[dj] = o.v;
  }
}

// ---------------- proj: 256x256x(BK=64) 8-wave 8-phase-style GEMM + epilogue ----
// A = xb [4096][512], B = w_cat [32768][512] (interleaved). 8 K-tiles of 64.
// LDS 128KB: A[2][256][64], B[2][256][64] bf16, XOR-swizzled 16B slots.
__global__ __launch_bounds__(512) void proj_kernel(
    const unsigned short* __restrict__ xb,
    const unsigned short* __restrict__ wcat,
    const float* __restrict__ b_dt, const float* __restrict__ b_B,
    const float* __restrict__ b_C, const float* __restrict__ b_V,
    const float* __restrict__ A_log,
    uint32* __restrict__ au,             // [4096][8192] u32: (vlog)<<16 | u
    unsigned short* __restrict__ c_out)  // [4096][8192] bf16: zC
{
  __shared__ __align__(16) unsigned short lds_all[65536];   // 128 KiB
  unsigned short* ldsA = lds_all;            // [2][256*64]
  unsigned short* ldsB = lds_all + 32768;    // [2][256*64]

  const int tid = threadIdx.x;
  const int lane = tid & 63;
  const int wave = tid >> 6;
  const int wr = wave >> 2;          // 0..1 : m half (128 rows)
  const int wc = wave & 3;           // 0..3 : n quarter (64 n_cat = 16ch x 4p)
  const int l15 = lane & 15, l4 = lane >> 4;
  const int bx = blockIdx.x;         // n_cat tile (128 tiles)
  const int m0 = blockIdx.y * 256;

  // stage one half-tile (16KB): kind 0/1 = A rows 0-127/128-255; 2/3 = B same.
  // LDS dest linear; global source k-slot deswizzled (rule #21).
  auto stage_half = [&](int bsel, int kt, int kind) {
    const int k0 = kt * 64;
    #pragma unroll
    for (int i = 0; i < 2; ++i) {
      const int s = i * 512 + tid;            // 0..1023 16B-slots
      const int rl = s >> 3, q = s & 7;
      const int row = (kind & 1) * 128 + rl;  // row in 256-tile
      const int ksrc = q ^ (row & 7);
      if (kind < 2) {
        const unsigned short* g = xb + (size_t)(m0 + row) * DIMK + k0 + ksrc * 8;
        __builtin_amdgcn_global_load_lds(
            (const __attribute__((address_space(1))) void*)g,
            (__attribute__((address_space(3))) void*)&ldsA[bsel * 16384 + row * 64 + q * 8],
            16, 0, 0);
      } else {
        const unsigned short* g = wcat + (size_t)(bx * 256 + row) * DIMK + k0 + ksrc * 8;
        __builtin_amdgcn_global_load_lds(
            (const __attribute__((address_space(1))) void*)g,
            (__attribute__((address_space(3))) void*)&ldsB[bsel * 16384 + row * 64 + q * 8],
            16, 0, 0);
      }
    }
  };

  f32x4 acc[8][4];
  #pragma unroll
  for (int fm = 0; fm < 8; ++fm)
    #pragma unroll
    for (int fn = 0; fn < 4; ++fn) acc[fm][fn] = (f32x4){0.f, 0.f, 0.f, 0.f};

  // prologue: stage tile 0 fully
  stage_half(0, 0, 0); stage_half(0, 0, 1); stage_half(0, 0, 2); stage_half(0, 0, 3);

  constexpr int NT = DIMK / 64;   // 8 K-tiles
  #pragma unroll 1
  for (int t = 0; t < NT; ++t) {
    const int bsel = t & 1;
    asm volatile("s_waitcnt vmcnt(0)" ::: "memory");
    __builtin_amdgcn_s_barrier();
    bf16x8 bfr[4];
    #pragma unroll
    for (int ph = 0; ph < 4; ++ph) {
      const int ks = ph >> 1, fmg = ph & 1;
      const int qk = ks * 4 + l4;
      bf16x8 af[4];
      #pragma unroll
      for (int i = 0; i < 4; ++i) {
        const int r = wr * 128 + (fmg * 4 + i) * 16 + l15;
        af[i] = *reinterpret_cast<const bf16x8*>(
            &ldsA[bsel * 16384 + r * 64 + (qk ^ (r & 7)) * 8]);
      }
      if (fmg == 0) {
        #pragma unroll
        for (int fn = 0; fn < 4; ++fn) {
          const int rb = wc * 64 + fn * 16 + l15;
          bfr[fn] = *reinterpret_cast<const bf16x8*>(
              &ldsB[bsel * 16384 + rb * 64 + (qk ^ (rb & 7)) * 8]);
        }
      }
      if (t + 1 < NT && ph < 2) {   // stage 2 half-tiles of next K-tile
        stage_half(bsel ^ 1, t + 1, ph * 2 + 0);
        stage_half(bsel ^ 1, t + 1, ph * 2 + 1);
      }
      __builtin_amdgcn_s_barrier();
      asm volatile("s_waitcnt lgkmcnt(0)" ::: "memory");
      __builtin_amdgcn_sched_barrier(0);
      __builtin_amdgcn_s_setprio(1);
      #pragma unroll
      for (int i = 0; i < 4; ++i)
        #pragma unroll
        for (int fn = 0; fn < 4; ++fn)
          acc[fmg * 4 + i][fn] = __builtin_amdgcn_mfma_f32_16x16x32_bf16(
              af[i], bfr[fn], acc[fmg * 4 + i][fn], 0, 0, 0);
      __builtin_amdgcn_s_setprio(0);
      __builtin_amdgcn_s_barrier();
    }
  }

  // epilogue: each thread owns ONE channel (all 4 projections via fn=p)
  const int ch = bx * 64 + wc * 16 + l15;
  const float vbdt = b_dt[ch], vbB = b_B[ch], vbC = b_C[ch], vbV = b_V[ch];
  const float al = A_log[ch];
  #pragma unroll
  for (int fm = 0; fm < 8; ++fm) {
    const int mb = m0 + wr * 128 + fm * 16 + l4 * 4;
    #pragma unroll
    for (int r = 0; r < 4; ++r) {
      const size_t off = (size_t)(mb + r) * NCH + ch;
      const float zdt = acc[fm][0][r] + vbdt;
      const float zB  = acc[fm][1][r] + vbB;
      const float zC  = acc[fm][2][r] + vbC;
      const float zV  = acc[fm][3][r] + vbV;
      const float dt = (zdt > 15.f) ? zdt : __logf(1.f + __expf(zdt));
      au[off] = ((uint32)f2bf(dt * al) << 16) | (uint32)f2bf(dt * zB * zV);
      c_out[off] = f2bf(zC);
    }
  }
}

// ---------------- chunked parallel scan (unchanged) ----------------
#define SCH 16
#define CSTEPS 128
__global__ __launch_bounds__(1024) void scan_kernel(
    const uint32* __restrict__ au,
    unsigned short* cy)
{
  __shared__ float Ap[SCH][64], He[SCH][64], H0[SCH][64];
  const int lane = threadIdx.x & 63;
  const int w = threadIdx.x >> 6;
  const int c = blockIdx.x * 64 + lane;
  const size_t base = (size_t)blockIdx.y * SEQL * NCH + (size_t)(w * CSTEPS) * NCH + c;

  {
    const uint32* ap = au + base;
    float h = 0.f, vsum = 0.f;
    #pragma unroll 1
    for (int s = 0; s < CSTEPS; s += 8) {
      uint32 wv[8];
      #pragma unroll
      for (int i = 0; i < 8; ++i) wv[i] = ap[(size_t)(s + i) * NCH];
      #pragma unroll
      for (int i = 0; i < 8; ++i) {
        const float av = bf2f((unsigned short)(wv[i] >> 16));
        const float uv = bf2f((unsigned short)(wv[i] & 0xffff));
        vsum += av;
        h = fmaf(__expf(av), h, uv);
      }
    }
    Ap[w][lane] = __expf(vsum);
    He[w][lane] = h;
  }
  __syncthreads();
  if (w == 0) {
    float run = 0.f;
    #pragma unroll
    for (int jj = 0; jj < SCH; ++jj) {
      H0[jj][lane] = run;
      run = fmaf(Ap[jj][lane], run, He[jj][lane]);
    }
  }
  __syncthreads();
  {
    const uint32* ap = au + base;
    unsigned short* cp = cy + base;
    float h = H0[w][lane];
    #pragma unroll 1
    for (int s = 0; s < CSTEPS; s += 8) {
      uint32 wv[8];
      float cv[8];
      #pragma unroll
      for (int i = 0; i < 8; ++i) {
        wv[i] = ap[(size_t)(s + i) * NCH];
        cv[i] = bf2f(cp[(size_t)(s + i) * NCH]);
      }
      #pragma unroll
      for (int i = 0; i < 8; ++i) {
        const float av = bf2f((unsigned short)(wv[i] >> 16));
        const float uv = bf2f((unsigned short)(wv[i] & 0xffff));
        h = fmaf(__expf(av), h, uv);
        cv[i] *= h;
      }
      #pragma unroll
      for (int i = 0; i < 8; ++i) cp[(size_t)(s + i) * NCH] = f2bf(cv[i]);
    }
  }
}

// swizzle for outproj (unchanged, 64B rows)
__device__ __forceinline__ int swz(int row, int q) { return q ^ ((row >> 2) & 3); }

// ---------------- output projection, split-K, 2-buffer ----------------
#define OLDS_A 4096   // 128*32
#define OLDS_B 2048   // 64*32
#define OLDS   (OLDS_A + OLDS_B)
__global__ __launch_bounds__(256) void outproj_kernel(
    const unsigned short* __restrict__ yb,    // [4096][8192] bf16
    const unsigned short* __restrict__ wout,  // [512][8192] bf16
    float* __restrict__ partial)              // [KS][4096][512] f32
{
  __shared__ __align__(16) unsigned short lds[2][OLDS];
  const int tid = threadIdx.x;
  const int lane = tid & 63;
  const int wave = tid >> 6;
  const int wr = wave >> 1, wc = wave & 1;
  const int m0 = blockIdx.x * 128;
  const int d0 = blockIdx.y * 64;
  const int kbase = blockIdx.z * (NCH / KS);   // 2048 per split

  auto stage = [&](int buf, int kt) {
    const int k0 = kbase + kt * 32;
    #pragma unroll
    for (int i = 0; i < 2; ++i) {
      int c = i * 256 + tid;
      int row = c >> 2, q = c & 3;
      const unsigned short* g = yb + (size_t)(m0 + row) * NCH + k0 + swz(row, q) * 8;
      __builtin_amdgcn_global_load_lds(
          (const __attribute__((address_space(1))) void*)g,
          (__attribute__((address_space(3))) void*)&lds[buf][c * 8], 16, 0, 0);
    }
    {
      int row = tid >> 2, q = tid & 3;
      const unsigned short* g = wout + (size_t)(d0 + row) * NCH + k0 + swz(row, q) * 8;
      __builtin_amdgcn_global_load_lds(
          (const __attribute__((address_space(1))) void*)g,
          (__attribute__((address_space(3))) void*)&lds[buf][OLDS_A + tid * 8], 16, 0, 0);
    }
  };

  f32x4 acc[4][2];
  #pragma unroll
  for (int fm = 0; fm < 4; ++fm)
    #pragma unroll
    for (int fn = 0; fn < 2; ++fn) acc[fm][fn] = (f32x4){0.f, 0.f, 0.f, 0.f};

  stage(0, 0);
  constexpr int NKT = (NCH / KS) / 32;   // 64
  #pragma unroll 1
  for (int kt = 0; kt < NKT; ++kt) {
    const int buf = kt & 1;
    if (kt + 1 < NKT) {
      stage(buf ^ 1, kt + 1);
      asm volatile("s_waitcnt vmcnt(3)" ::: "memory");
    } else {
      asm volatile("s_waitcnt vmcnt(0)" ::: "memory");
    }
    __builtin_amdgcn_s_barrier();

    const int qq = lane >> 4;
    bf16x8 af[4], bfr[2];
    #pragma unroll
    for (int fm = 0; fm < 4; ++fm) {
      const int r = wr * 64 + fm * 16 + (lane & 15);
      af[fm] = *reinterpret_cast<const bf16x8*>(&lds[buf][r * 32 + swz(r, qq) * 8]);
    }
    #pragma unroll
    for (int fn = 0; fn < 2; ++fn) {
      const int r = wc * 32 + fn * 16 + (lane & 15);
      bfr[fn] = *reinterpret_cast<const bf16x8*>(
          &lds[buf][OLDS_A + r * 32 + swz(r, qq) * 8]);
    }
    __builtin_amdgcn_s_setprio(1);
    #pragma unroll
    for (int fm = 0; fm < 4; ++fm)
      #pragma unroll
      for (int fn = 0; fn < 2; ++fn)
        acc[fm][fn] = __builtin_amdgcn_mfma_f32_16x16x32_bf16(
            af[fm], bfr[fn], acc[fm][fn], 0, 0, 0);
    __builtin_amdgcn_s_setprio(0);
    asm volatile("s_waitcnt lgkmcnt(0)" ::: "memory");
    __builtin_amdgcn_s_barrier();
  }

  float* pout = partial + (size_t)blockIdx.z * MTOT * DIMK;
  #pragma unroll
  for (int fn = 0; fn < 2; ++fn) {
    const int d = d0 + wc * 32 + fn * 16 + (lane & 15);
    #pragma unroll
    for (int fm = 0; fm < 4; ++fm) {
      const int mbase = m0 + wr * 64 + fm * 16 + (lane >> 4) * 4;
      #pragma unroll
      for (int r = 0; r < 4; ++r)
        pout[(size_t)(mbase + r) * DIMK + d] = acc[fm][fn][r];
    }
  }
}

// ---------------- split-K reduce + bias ----------------
__global__ __launch_bounds__(256) void reduce_kernel(
    const float* __restrict__ p, const float* __restrict__ bias,
    float* __restrict__ out)
{
  const int i = blockIdx.x * 256 + threadIdx.x;   // float4 index, 524288 total
  const float4* p4 = reinterpret_cast<const float4*>(p);
  float4 s = p4[i];
  #pragma unroll
  for (int k = 1; k < KS; ++k) {
    float4 t = p4[(size_t)k * (MTOT * DIMK / 4) + i];
    s.x += t.x; s.y += t.y; s.z += t.z; s.w += t.w;
  }
  const float4 b = reinterpret_cast<const float4*>(bias)[i & 127];
  s.x += b.x; s.y += b.y; s.z += b.z; s.w += b.w;
  reinterpret_cast<float4*>(out)[i] = s;
}

extern "C" void kernel_launch(void* const* d_in, const int* in_sizes, int n_in,
                              void* d_out, int out_size, void* d_ws, size_t ws_size,
                              hipStream_t stream) {
  const float* x    = (const float*)d_in[0];
  const float* Wdt  = (const float*)d_in[1];
  const float* bdt  = (const float*)d_in[2];
  const float* WB   = (const float*)d_in[3];
  const float* bB   = (const float*)d_in[4];
  const float* WC   = (const float*)d_in[5];
  const float* bC   = (const float*)d_in[6];
  const float* WV   = (const float*)d_in[7];
  const float* bV   = (const float*)d_in[8];
  const float* Alog = (const float*)d_in[9];
  const float* Wout = (const float*)d_in[10];
  const float* bout = (const float*)d_in[11];
  float* out = (float*)d_out;

  char* ws = (char*)d_ws;
  unsigned short* woutb = (unsigned short*)(ws);               // 8 MiB
  unsigned short* xb    = (unsigned short*)(ws + 8388608);     // 4 MiB
  unsigned short* wcat  = (unsigned short*)(ws + 12582912);    // 32 MiB interleaved
  char* dyn = ws + 46137344;
  uint32*         au  = (uint32*)(dyn);                        // 128 MiB
  unsigned short* cy  = (unsigned short*)(dyn + (size_t)MTOT * NCH * 4);  // 64 MiB
  float* partial = (float*)au;   // alias: au dead after scan; KS*4096*512*4 = 32 MiB

  CvtArgs ca;
  ca.src[0] = x;    ca.dst[0] = xb;
  ca.src[1] = Wdt;  ca.dst[1] = wcat;
  ca.src[2] = WB;   ca.dst[2] = wcat;
  ca.src[3] = WC;   ca.dst[3] = wcat;
  ca.src[4] = WV;   ca.dst[4] = wcat;
  ca.src[5] = Wout; ca.dst[5] = woutb;
  ca.cum[0] = 0;        ca.cum[1] = 262144;  ca.cum[2] = 786432;
  ca.cum[3] = 1310720;  ca.cum[4] = 1835008; ca.cum[5] = 2359296;
  ca.cum[6] = 2883584;
  cvt_all_kernel<<<2048, 256, 0, stream>>>(ca, 2883584);

  proj_kernel<<<dim3(NCAT / 256, MTOT / 256), 512, 0, stream>>>(
      xb, wcat, bdt, bB, bC, bV, Alog, au, cy);
  scan_kernel<<<dim3(NCH / 64, 2), 1024, 0, stream>>>(au, cy);
  outproj_kernel<<<dim3(MTOT / 128, DIMK / 64, KS), 256, 0, stream>>>(
      cy, woutb, partial);
  reduce_kernel<<<MTOT * DIMK / 4 / 256, 256, 0, stream>>>(partial, bout, out);
}